// Round 1
// baseline (1107.644 us; speedup 1.0000x reference)
//
#include <hip/hip_runtime.h>

#define IC   256
#define OCH  128
#define KS   3
#define BSZ  16
#define IH   64
#define IW   64
#define OH2  128
#define OW2  128
#define QMAXF 127.0f

// ws float layout
#define WS_WSCALE 0
#define WS_ASCALE 256
#define WS_SCALE  512
#define WS_SX     768
#define WS_SW     769
#define WS_F      770
#define WS_QW     1024   // [9][128][256] floats (tap, oc, ic)

// ---------------- K1: per-channel maxes ----------------
__global__ __launch_bounds__(256) void k_channel_scales(
        const float* __restrict__ x, const float* __restrict__ w,
        float* __restrict__ ws) {
    const int ic = blockIdx.x;
    const int t  = threadIdx.x;
    float wmax = 0.f, amax = 0.f;
    for (int j = t; j < OCH * KS * KS; j += 256)
        wmax = fmaxf(wmax, fabsf(w[ic * (OCH * KS * KS) + j]));
    for (int b = 0; b < BSZ; ++b) {
        const float* xp = x + ((size_t)(b * IC + ic)) * (IH * IW);
        for (int hw = t; hw < IH * IW; hw += 256)
            amax = fmaxf(amax, fabsf(xp[hw]));
    }
    __shared__ float r1[256], r2[256];
    r1[t] = wmax; r2[t] = amax;
    __syncthreads();
    for (int s = 128; s > 0; s >>= 1) {
        if (t < s) {
            r1[t] = fmaxf(r1[t], r1[t + s]);
            r2[t] = fmaxf(r2[t], r2[t + s]);
        }
        __syncthreads();
    }
    if (t == 0) { ws[WS_WSCALE + ic] = r1[0]; ws[WS_ASCALE + ic] = r2[0]; }
}

// ---------------- K2: scales + per-tensor quant steps ----------------
__global__ __launch_bounds__(256) void k_finalize(float* __restrict__ ws) {
    const int t = threadIdx.x;
    const float wsc = ws[WS_WSCALE + t];
    const float asc = ws[WS_ASCALE + t];
    float sc = sqrtf(asc) / sqrtf(wsc);
    if (sc == 0.f) sc = 1.f;
    ws[WS_SCALE + t] = sc;
    // monotonicity: elementwise max of fl(|w|*sc) == fl(wsc*sc); same for division
    float wm = wsc * sc;
    float am = asc / sc;
    __shared__ float r1[256], r2[256];
    r1[t] = wm; r2[t] = am;
    __syncthreads();
    for (int s = 128; s > 0; s >>= 1) {
        if (t < s) {
            r1[t] = fmaxf(r1[t], r1[t + s]);
            r2[t] = fmaxf(r2[t], r2[t + s]);
        }
        __syncthreads();
    }
    if (t == 0) {
        float sw = r1[0] / QMAXF; if (sw == 0.f) sw = 1.f;
        float sx = r2[0] / QMAXF; if (sx == 0.f) sx = 1.f;
        ws[WS_SX] = sx; ws[WS_SW] = sw; ws[WS_F] = sx * sw;
    }
}

// ---------------- K3: quantize weights -> ws[WS_QW] as float ints ----------------
// qw layout: [tap][oc][ic], tap = di*3+dj
__global__ __launch_bounds__(256) void k_quant_w(
        const float* __restrict__ w, float* __restrict__ ws) {
    const int idx = blockIdx.x * 256 + threadIdx.x;   // tap*32768 + oc*256 + ic
    const int tap = idx >> 15;
    const int oc  = (idx >> 8) & 127;
    const int ic  = idx & 255;
    const float sw = ws[WS_SW];
    const float val = w[(ic * OCH + oc) * 9 + tap] * ws[WS_SCALE + ic];
    float q = rintf(val / sw);
    q = fminf(fmaxf(q, -128.f), 127.f);
    ws[WS_QW + idx] = q;
}

// ---------------- K5: fused quantize-x + int-GEMM + col2im + bias ----------------
template<int T, int R, int OFF>
__device__ __forceinline__ void do_tap(const signed char* qb, const float* __restrict__ wq,
                                       int oc0, int lane, float* acc) {
    // force wave-uniform so the weight reads become s_loads
    const int woff = __builtin_amdgcn_readfirstlane((T * OCH + oc0) * IC);
    const int base = R * IC * 68 + lane + OFF;
    #pragma unroll 4
    for (int ic = 0; ic < IC; ++ic) {
        const float xf = (float)qb[base + ic * 68];
        #pragma unroll
        for (int j = 0; j < 16; ++j)
            acc[j] = fmaf(xf, wq[woff + j * IC + ic], acc[j]);
    }
}

__global__ __launch_bounds__(512) void k_conv(
        const float* __restrict__ x, const float* __restrict__ bias,
        const float* __restrict__ ws, float* __restrict__ out) {
    // int8 LDS tile: [row 0..1][ic][68 bytes: 64 wi + 4B zero pad]
    __shared__ int qx4[2 * 256 * 17];
    const int tid = threadIdx.x;
    const int u = blockIdx.x;     // input row pair base; out rows 2u, 2u+1
    const int b = blockIdx.y;
    const float sx = ws[WS_SX];
    const float f  = ws[WS_F];

    for (int i = tid; i < 2 * 256 * 17; i += 512) qx4[i] = 0;
    __syncthreads();

    {   // quantize input rows u, u+1 into LDS
        const int wi4 = tid & 15;      // 4-float column group
        const int icb = tid >> 4;      // 0..31
        for (int hi = 0; hi < 2; ++hi) {
            const int row = u + hi;
            if (row >= IH) break;      // zero-padded bottom row
            for (int ic = icb; ic < IC; ic += 32) {
                const float4 v = *(const float4*)(
                    x + (((size_t)(b * IC + ic)) * IH + row) * IW + wi4 * 4);
                const float sc = ws[WS_SCALE + ic];
                const int q0 = (int)fminf(fmaxf(rintf((v.x / sc) / sx), -128.f), 127.f);
                const int q1 = (int)fminf(fmaxf(rintf((v.y / sc) / sx), -128.f), 127.f);
                const int q2 = (int)fminf(fmaxf(rintf((v.z / sc) / sx), -128.f), 127.f);
                const int q3 = (int)fminf(fmaxf(rintf((v.w / sc) / sx), -128.f), 127.f);
                qx4[(hi * IC + ic) * 17 + wi4] =
                    (q0 & 255) | ((q1 & 255) << 8) | ((q2 & 255) << 16) | ((q3 & 255) << 24);
            }
        }
    }
    __syncthreads();

    const signed char* qb = (const signed char*)qx4;
    const int lane = tid & 63;         // column position v; ow = 2v+par
    const int wid  = tid >> 6;         // 8 waves
    const int oc0  = wid * 16;         // 16 output channels per wave
    const float* wq = ws + WS_QW;

    #pragma unroll
    for (int oh_sel = 0; oh_sel < 2; ++oh_sel) {
        float acc0[16], acc1[16];      // par0: ow=2v (owp odd, dj=1); par1: ow=2v+1 (dj=0@wi+1, dj=2@wi)
        #pragma unroll
        for (int j = 0; j < 16; ++j) { acc0[j] = 0.f; acc1[j] = 0.f; }

        if (oh_sel == 0) {
            // oh = 2u, ohp odd -> di=1, input row u (LDS row 0); taps t = 3+dj
            do_tap<4, 0, 0>(qb, wq, oc0, lane, acc0);
            do_tap<3, 0, 1>(qb, wq, oc0, lane, acc1);
            do_tap<5, 0, 0>(qb, wq, oc0, lane, acc1);
        } else {
            // oh = 2u+1, ohp even -> di=0 @ row u+1 (LDS row 1), di=2 @ row u (LDS row 0)
            do_tap<1, 1, 0>(qb, wq, oc0, lane, acc0);
            do_tap<0, 1, 1>(qb, wq, oc0, lane, acc1);
            do_tap<2, 1, 0>(qb, wq, oc0, lane, acc1);
            do_tap<7, 0, 0>(qb, wq, oc0, lane, acc0);
            do_tap<6, 0, 1>(qb, wq, oc0, lane, acc1);
            do_tap<8, 0, 0>(qb, wq, oc0, lane, acc1);
        }

        const int oh = 2 * u + oh_sel;
        #pragma unroll
        for (int j = 0; j < 16; ++j) {
            const int oc = oc0 + j;
            const float bval = bias[oc];
            float2 o;
            o.x = fmaf(acc0[j], f, bval);
            o.y = fmaf(acc1[j], f, bval);
            *(float2*)(out + (((size_t)(b * OCH + oc)) * OH2 + oh) * OW2 + 2 * lane) = o;
        }
    }
}

extern "C" void kernel_launch(void* const* d_in, const int* in_sizes, int n_in,
                              void* d_out, int out_size, void* d_ws, size_t ws_size,
                              hipStream_t stream) {
    const float* x    = (const float*)d_in[0];
    const float* w    = (const float*)d_in[1];
    const float* bias = (const float*)d_in[2];
    float* ws  = (float*)d_ws;
    float* out = (float*)d_out;

    k_channel_scales<<<256, 256, 0, stream>>>(x, w, ws);
    k_finalize<<<1, 256, 0, stream>>>(ws);
    k_quant_w<<<(9 * OCH * IC) / 256, 256, 0, stream>>>(w, ws);
    dim3 grid(IH, BSZ);   // (u, b)
    k_conv<<<grid, 512, 0, stream>>>(x, bias, ws, out);
}

// Round 2
// 139.213 us; speedup vs baseline: 7.9565x; 7.9565x over previous
//
#include <hip/hip_runtime.h>

typedef __attribute__((ext_vector_type(8))) short bf16x8;
typedef __attribute__((ext_vector_type(16))) float f32x16;

#define IC   256
#define OCH  128
#define BSZ  16
#define IH   64
#define IW   64
#define OH2  128
#define OW2  128
#define QMAXF 127.0f

// ws float-offset layout
#define WS_WSCALE 0        // 256 per-ic weight absmax
#define WS_APART  256      // 8*256 per-(bq,ic) act absmax partials
#define WS_QS     2304     // 256: x multiplier 1/(sc*sx)
#define WS_WQS    2560     // 256: w multiplier sc/sw
#define WS_F      2816     // sx*sw
#define WS_WQ     3072     // bf16[9][128][256] quantized weights (589824 B)

// ---------------- K1: per-channel absmax (partials over batch) ----------------
__global__ __launch_bounds__(256) void k_channel_scales(
        const float* __restrict__ x, const float* __restrict__ w,
        float* __restrict__ ws) {
    const int ic = blockIdx.x;
    const int bq = blockIdx.y;          // 0..7, two batches each
    const int t  = threadIdx.x;
    float amax = 0.f, wmax = 0.f;
    for (int bb = 2 * bq; bb < 2 * bq + 2; ++bb) {
        const float* xp = x + ((size_t)(bb * IC + ic)) * (IH * IW);
        for (int hw = t * 4; hw < IH * IW; hw += 1024) {
            float4 v = *(const float4*)(xp + hw);
            amax = fmaxf(amax, fmaxf(fmaxf(fabsf(v.x), fabsf(v.y)),
                                     fmaxf(fabsf(v.z), fabsf(v.w))));
        }
    }
    if (bq == 0)
        for (int j = t; j < OCH * 9; j += 256)
            wmax = fmaxf(wmax, fabsf(w[ic * (OCH * 9) + j]));
    __shared__ float r1[256], r2[256];
    r1[t] = wmax; r2[t] = amax;
    __syncthreads();
    for (int s = 128; s > 0; s >>= 1) {
        if (t < s) {
            r1[t] = fmaxf(r1[t], r1[t + s]);
            r2[t] = fmaxf(r2[t], r2[t + s]);
        }
        __syncthreads();
    }
    if (t == 0) {
        ws[WS_APART + bq * 256 + ic] = r2[0];
        if (bq == 0) ws[WS_WSCALE + ic] = r1[0];
    }
}

// ---------------- K2: scales + per-tensor quant steps ----------------
__global__ __launch_bounds__(256) void k_finalize(float* __restrict__ ws) {
    const int t = threadIdx.x;          // = ic
    float asc = 0.f;
    for (int q = 0; q < 8; ++q) asc = fmaxf(asc, ws[WS_APART + q * 256 + t]);
    const float wsc = ws[WS_WSCALE + t];
    float sc = sqrtf(asc) / sqrtf(wsc);
    if (sc == 0.f) sc = 1.f;
    float wm = wsc * sc;                // elementwise max of |w*sc| (monotone)
    float am = asc / sc;                // elementwise max of |x/sc|
    __shared__ float r1[256], r2[256];
    r1[t] = wm; r2[t] = am;
    __syncthreads();
    for (int s = 128; s > 0; s >>= 1) {
        if (t < s) {
            r1[t] = fmaxf(r1[t], r1[t + s]);
            r2[t] = fmaxf(r2[t], r2[t + s]);
        }
        __syncthreads();
    }
    float sw = r1[0] / QMAXF; if (sw == 0.f) sw = 1.f;
    float sx = r2[0] / QMAXF; if (sx == 0.f) sx = 1.f;
    ws[WS_QS  + t] = 1.f / (sc * sx);
    ws[WS_WQS + t] = sc / sw;
    if (t == 0) ws[WS_F] = sx * sw;
}

// ---------------- K3: quantize weights -> bf16 (exact small ints) ----------------
// layout: wqb[tap][oc][ic]
__global__ __launch_bounds__(256) void k_quant_w(
        const float* __restrict__ w, float* __restrict__ ws) {
    const int idx = blockIdx.x * 256 + threadIdx.x;
    const int tap = idx >> 15;
    const int oc  = (idx >> 8) & 127;
    const int ic  = idx & 255;
    float q = rintf(w[(ic * OCH + oc) * 9 + tap] * ws[WS_WQS + ic]);
    q = fminf(fmaxf(q, -128.f), 127.f);
    ((unsigned short*)(ws + WS_WQ))[idx] =
        (unsigned short)(__builtin_bit_cast(unsigned, q) >> 16);
}

// ---------------- K4: MFMA conv ----------------
// LDS x-tile: bf16 [r(2)][v(65)][ic(256)], byte = (r*65+v)*512 + ((2*ic) ^ ((v&15)<<4))
__device__ __forceinline__ bf16x8 load_a(const char* smem, int r, int vbase, int k0, int lane) {
    const int v = vbase + (lane & 31);
    const unsigned byte = (unsigned)((r * 65 + v) * 512)
        + (((unsigned)(2 * k0 + ((lane >> 5) << 4))) ^ ((unsigned)(v & 15) << 4));
    return *(const bf16x8*)(smem + byte);
}

__device__ __forceinline__ bf16x8 load_b(const unsigned short* wqb, int tap, int oc, int k0, int lane) {
    const unsigned short* p = wqb + (size_t)(tap * OCH + oc) * IC + k0 + ((lane >> 5) << 3);
    return *(const bf16x8*)p;
}

template<int NN, int T, int R, int S>
__device__ __forceinline__ void do_tap_g(const char* smem, const unsigned short* wqb,
                                         int ocbase, int lane, int k0, f32x16 (&acc)[2][2]) {
    bf16x8 a0 = load_a(smem, R, S,      k0, lane);
    bf16x8 a1 = load_a(smem, R, S + 32, k0, lane);
    #pragma unroll
    for (int n = 0; n < NN; ++n) {
        bf16x8 bb = load_b(wqb, T, ocbase + n * 32 + (lane & 31), k0, lane);
        acc[0][n] = __builtin_amdgcn_mfma_f32_32x32x16_bf16(a0, bb, acc[0][n], 0, 0, 0);
        acc[1][n] = __builtin_amdgcn_mfma_f32_32x32x16_bf16(a1, bb, acc[1][n], 0, 0, 0);
    }
}

template<int NN, int T0,int R0,int S0, int T1,int R1,int S1,
         int T2,int R2,int S2, int T3,int R3,int S3>
__device__ __forceinline__ void run_gemm(const char* smem, const unsigned short* wqb,
                                         int ocbase, int lane, f32x16 (&acc)[2][2]) {
    #pragma unroll 2
    for (int ks = 0; ks < 16; ++ks) {
        const int k0 = ks * 16;
        do_tap_g<NN, T0, R0, S0>(smem, wqb, ocbase, lane, k0, acc);
        if constexpr (T1 >= 0) do_tap_g<NN, T1, R1, S1>(smem, wqb, ocbase, lane, k0, acc);
        if constexpr (T2 >= 0) do_tap_g<NN, T2, R2, S2>(smem, wqb, ocbase, lane, k0, acc);
        if constexpr (T3 >= 0) do_tap_g<NN, T3, R3, S3>(smem, wqb, ocbase, lane, k0, acc);
    }
}

__global__ __launch_bounds__(640) void k_conv(
        const float* __restrict__ x, const float* __restrict__ bias,
        const float* __restrict__ ws, float* __restrict__ out) {
    __shared__ char smem[66560];
    const int tid = threadIdx.x;
    const int u = blockIdx.x;           // out rows 2u, 2u+1
    const int b = blockIdx.y;
    const int lane = tid & 63;
    const int wid  = tid >> 6;          // 0..9

    // zero LDS (pad column v=64 and possibly-missing row u+1 must be 0)
    int* sm4 = (int*)smem;
    for (int i = tid; i < 66560 / 4; i += 640) sm4[i] = 0;
    __syncthreads();

    // stage + quantize x rows u, u+1 -> bf16 LDS
    unsigned* lds32 = (unsigned*)smem;
    for (int it = tid; it < 4096; it += 640) {
        const int v4  = it & 15;         // 4-column group
        const int icp = (it >> 4) & 127; // ic pair
        const int r   = it >> 11;
        const int row = u + r;
        if (row < IH) {
            const int ic0 = icp * 2;
            const float* p0 = x + (((size_t)(b * IC + ic0)) * IH + row) * IW + v4 * 4;
            const float4 a0 = *(const float4*)p0;
            const float4 a1 = *(const float4*)(p0 + (size_t)IH * IW);
            const float q0 = ws[WS_QS + ic0], q1 = ws[WS_QS + ic0 + 1];
            const float e0[4] = {a0.x, a0.y, a0.z, a0.w};
            const float e1[4] = {a1.x, a1.y, a1.z, a1.w};
            #pragma unroll
            for (int i = 0; i < 4; ++i) {
                const int v = v4 * 4 + i;
                float f0 = fminf(fmaxf(rintf(e0[i] * q0), -128.f), 127.f);
                float f1 = fminf(fmaxf(rintf(e1[i] * q1), -128.f), 127.f);
                unsigned word = (__builtin_bit_cast(unsigned, f0) >> 16)
                              | ((__builtin_bit_cast(unsigned, f1) >> 16) << 16);
                unsigned byte = (unsigned)((r * 65 + v) * 512)
                              + (((unsigned)(4 * icp)) ^ ((unsigned)(v & 15) << 4));
                lds32[byte >> 2] = word;
            }
        }
    }
    __syncthreads();

    const unsigned short* wqb = (const unsigned short*)(ws + WS_WQ);
    const float fscale = ws[WS_F];

    f32x16 acc[2][2];
    const f32x16 z = (f32x16)(0.f);
    acc[0][0] = z; acc[0][1] = z; acc[1][0] = z; acc[1][1] = z;

    // classes: wid 0,1: (row0,par0) tap4@(r0,+0)            | oc half
    //          wid 2,3: (row0,par1) tap3@(r0,+1) tap5@(r0,0)| oc half
    //          wid 4,5: (row1,par0) tap1@(r1,0)  tap7@(r0,0)| oc half
    //          wid 6-9: (row1,par1) taps 0@(r1,+1) 2@(r1,0) 6@(r0,+1) 8@(r0,0) | oc quarter
    int ocbase, par, myrow, nnw;
    if (wid < 2) {
        ocbase = (wid & 1) * 64; par = 0; myrow = 0; nnw = 2;
        run_gemm<2, 4,0,0, -1,0,0, -1,0,0, -1,0,0>(smem, wqb, ocbase, lane, acc);
    } else if (wid < 4) {
        ocbase = (wid & 1) * 64; par = 1; myrow = 0; nnw = 2;
        run_gemm<2, 3,0,1, 5,0,0, -1,0,0, -1,0,0>(smem, wqb, ocbase, lane, acc);
    } else if (wid < 6) {
        ocbase = (wid & 1) * 64; par = 0; myrow = 1; nnw = 2;
        run_gemm<2, 1,1,0, 7,0,0, -1,0,0, -1,0,0>(smem, wqb, ocbase, lane, acc);
    } else {
        ocbase = (wid - 6) * 32; par = 1; myrow = 1; nnw = 1;
        run_gemm<1, 0,1,1, 2,1,0, 6,0,1, 8,0,0>(smem, wqb, ocbase, lane, acc);
    }

    // epilogue: transpose C through LDS (reuse x-tile space), coalesced store
    float* cst = (float*)smem;          // [oc][129] floats, stride 129 -> conflict-free
    #pragma unroll
    for (int phase = 0; phase < 2; ++phase) {
        __syncthreads();                // previous use of smem complete
        if (myrow == phase) {
            #pragma unroll
            for (int m = 0; m < 2; ++m)
                #pragma unroll
                for (int n = 0; n < 2; ++n) {
                    if (n < nnw) {
                        const int oc = ocbase + n * 32 + (lane & 31);
                        #pragma unroll
                        for (int reg = 0; reg < 16; ++reg) {
                            const int v = m * 32 + (reg & 3) + 8 * (reg >> 2) + 4 * (lane >> 5);
                            cst[oc * 129 + 2 * v + par] = acc[m][n][reg];
                        }
                    }
                }
        }
        __syncthreads();
        const int oh = 2 * u + phase;
        for (int idx = tid; idx < 16384; idx += 640) {
            const int oc = idx >> 7, ow = idx & 127;
            const float vv = cst[oc * 129 + ow];
            out[(((size_t)(b * OCH + oc)) * OH2 + oh) * OW2 + ow] =
                fmaf(vv, fscale, bias[oc]);
        }
    }
}

extern "C" void kernel_launch(void* const* d_in, const int* in_sizes, int n_in,
                              void* d_out, int out_size, void* d_ws, size_t ws_size,
                              hipStream_t stream) {
    const float* x    = (const float*)d_in[0];
    const float* w    = (const float*)d_in[1];
    const float* bias = (const float*)d_in[2];
    float* ws  = (float*)d_ws;
    float* out = (float*)d_out;

    k_channel_scales<<<dim3(256, 8), 256, 0, stream>>>(x, w, ws);
    k_finalize<<<1, 256, 0, stream>>>(ws);
    k_quant_w<<<(9 * OCH * IC) / 256, 256, 0, stream>>>(w, ws);
    k_conv<<<dim3(IH, BSZ), 640, 0, stream>>>(x, bias, ws, out);
}